// Round 9
// baseline (222.840 us; speedup 1.0000x reference)
//
#include <hip/hip_runtime.h>
#include <stdint.h>

#define B_   32
#define CIN  128
#define HH   96
#define WW   96
#define HW   (HH*WW)        // 9216
#define NPIX (B_*HW)        // 294912
#define AROWS 144
#define APAD  136           // bf16 elems per Asm row (272 B)
#define SCALE 0.08838834764831845f  // 1/sqrt(128)
#define ESW   97            // Es row stride (odd -> bank spread)
#define ESN   (18*ESW)      // f32 per Es buffer (1746)

// ws layout (bytes)
#define AB_OFF 0u
#define V_OFF  36864u
#define S_OFF  37376u
#define Y2_OFF 40960u
#define Z2_OFF (Y2_OFF + 75497472u)
#define ZP_OFF (Z2_OFF + 1179648u)          // 16 KB zero page
#define WS_NEED (ZP_OFF + 16384u)

typedef __attribute__((ext_vector_type(8))) short bf16x8;
typedef __attribute__((ext_vector_type(4))) float f32x4;

__device__ inline unsigned short f2bf(float f) {
    unsigned int u = __float_as_uint(f);
    u += 0x7fffu + ((u >> 16) & 1u);   // round-to-nearest-even
    return (unsigned short)(u >> 16);
}

// in-row XOR swizzle for 128B-aligned rows of 64 bf16: bijective (bits 4-6)
__device__ inline int bswz(int row, int byteoff) {
    return row * 128 + (byteoff ^ (((row ^ (row >> 3)) & 7) << 4));
}

// ---------------- K1: Abuf = [W^T W ; v ; 0], vbuf, sbuf, zero-page --------
__global__ __launch_bounds__(128) void k1_prep(
    const float* __restrict__ Wm, const float* __restrict__ bias,
    unsigned short* __restrict__ Abuf, float* __restrict__ vbuf,
    float* __restrict__ sbuf, char* __restrict__ zp) {
    int r = blockIdx.x;      // 0..143
    int c = threadIdx.x;     // 0..127
    int gid = r * 128 + c;
    if (gid < 1024)
        *(uint4*)(zp + gid * 16) = make_uint4(0u, 0u, 0u, 0u);

    float acc = 0.f;
    if (r < 128) {
        for (int f = 0; f < 128; ++f)
            acc += Wm[f * 128 + r] * Wm[f * 128 + c];
    } else if (r == 128) {
        for (int f = 0; f < 128; ++f)
            acc += Wm[f * 128 + c] * bias[f];
        vbuf[c] = acc;
        if (c == 0) {
            float s = 0.f;
            for (int f = 0; f < 128; ++f) s += bias[f] * bias[f];
            sbuf[0] = s;
        }
    }
    Abuf[r * 128 + c] = f2bf(acc);
}

// ---- K2: y2[seg][b][hw][8ch] = (M a2 + v) bf16 planar; z2 = v.a2 + s ------
__global__ __launch_bounds__(512, 4) void k2_proj(
    const float* __restrict__ a2, const unsigned short* __restrict__ Abuf,
    const float* __restrict__ vbuf, const float* __restrict__ sbuf,
    unsigned short* __restrict__ y2, float* __restrict__ z2) {
    __shared__ __align__(16) unsigned short Asm[AROWS * APAD];   // 39168 B
    __shared__ __align__(128) unsigned char Bsm[2][128 * 128];   // 32768 B

    const int t = threadIdx.x;
    const int tile = blockIdx.x;          // 0..2303
    const int b = tile / 72;
    const int hw0 = (tile - b * 72) * 128;

    for (int i = t; i < 2304; i += 512) {
        int row = i >> 4, seg = i & 15;
        *(uint4*)(&Asm[row * APAD + seg * 8]) =
            *(const uint4*)(Abuf + row * 128 + seg * 8);
    }

    {
        const int pxq = t & 31;           // px quad 0..31
        const int ctp = t >> 5;           // ch-pair 0..15
        const float* a2b = a2 + (size_t)b * (CIN * HW) + hw0 + pxq * 4;
#pragma unroll
        for (int it = 0; it < 4; ++it) {
            const int cc0 = (ctp + it * 16) * 2;      // even channel
            float4 f0 = *(const float4*)(a2b + (size_t)cc0 * HW);
            float4 f1 = *(const float4*)(a2b + (size_t)(cc0 + 1) * HW);
            unsigned char* pl = Bsm[cc0 >> 6];
            const int bo = (cc0 & 63) * 2;
            float a0[4] = {f0.x, f0.y, f0.z, f0.w};
            float a1[4] = {f1.x, f1.y, f1.z, f1.w};
#pragma unroll
            for (int r = 0; r < 4; ++r) {
                unsigned int pk = (unsigned int)f2bf(a0[r]) |
                                  ((unsigned int)f2bf(a1[r]) << 16);
                *(unsigned int*)(&pl[bswz(pxq * 4 + r, bo)]) = pk;
            }
        }
    }
    __syncthreads();

    const int wv = t >> 6;
    const int l = t & 63;
    const int li = l & 15;
    const int hi = l >> 4;
    const int rbase = hi * 4;
    const int pxl = wv * 16 + li;

    bf16x8 bfr[4];
#pragma unroll
    for (int kk = 0; kk < 4; ++kk) {
        const int k0 = kk * 32 + hi * 8;
        bfr[kk] = *(const bf16x8*)(&Bsm[k0 >> 6][bswz(pxl, (k0 & 63) * 2)]);
    }

    f32x4 acc[9];
#pragma unroll
    for (int m = 0; m < 9; ++m) acc[m] = (f32x4){0.f, 0.f, 0.f, 0.f};

#pragma unroll
    for (int kk = 0; kk < 4; ++kk) {
        const int k0 = kk * 32 + hi * 8;
#pragma unroll
        for (int m = 0; m < 9; ++m) {
            bf16x8 af = *(const bf16x8*)(&Asm[(m * 16 + li) * APAD + k0]);
            acc[m] = __builtin_amdgcn_mfma_f32_16x16x32_bf16(af, bfr[kk], acc[m], 0, 0, 0);
        }
    }

    const int px = hw0 + pxl;
    const size_t pxoff = (size_t)b * HW + px;
#pragma unroll
    for (int m = 0; m < 8; ++m) {
        int c0 = m * 16 + rbase;
        ushort4 pk;
        pk.x = f2bf(acc[m].x + vbuf[c0 + 0]);
        pk.y = f2bf(acc[m].y + vbuf[c0 + 1]);
        pk.z = f2bf(acc[m].z + vbuf[c0 + 2]);
        pk.w = f2bf(acc[m].w + vbuf[c0 + 3]);
        *(ushort4*)(y2 + ((size_t)(c0 >> 3) * NPIX + pxoff) * 8 + (c0 & 7)) = pk;
    }
    if (rbase == 0) {
        z2[pxoff] = acc[8].x + sbuf[0];
    }
}

// -------- K3: MFMA correlation, 2 image rows packed per 16-row A-tile ------
// A rows 0-7 = row h px window, rows 8-15 = row h+1 same window.
// Round di (0..9): B row hs = h-4+di; plane0 shift-row di, plane1 shift-row di-1.
// Streamed epilogue: rows completed at round di staged in a double-buffered
// 18-row Es (aliasing Xs), stored as full 384B-aligned lines next round.
__global__ __launch_bounds__(256, 3) void k3_corr(
    const float* __restrict__ x1, const char* __restrict__ wsb,
    float* __restrict__ out) {
    // Xs: [2 im][2 chplane][96 rows][64 bf16] = 49152 B ; Es alias: 13968 B
    __shared__ __align__(128) unsigned char EX[49152];
    float* Es = (float*)EX;

    const int t = threadIdx.x;
    const int bx = blockIdx.x;                 // 0..47
    const int b = blockIdx.y;
    const int h = ((bx & 7) * 6 + (bx >> 3)) * 2;   // XCD-chunked, bijective

    const int wv = t >> 6;       // wave 0..3
    const int l = t & 63;
    const int li = l & 15;
    const int hi = l >> 4;

    // stage Xs: 2 image rows, [128 ch][96 px] f32 -> swizzled bf16 planes
    {
        const float* x1b = x1 + (size_t)b * (CIN * HW) + (size_t)h * 96;
#pragma unroll
        for (int im = 0; im < 2; ++im) {
            const float* xr = x1b + im * 96;
#pragma unroll
            for (int it = 0; it < 6; ++it) {
                int idx = t + it * 256;           // 0..1535
                int ccp = idx / 24;               // 0..63
                int pxq = idx - ccp * 24;         // 0..23
                int cc0 = ccp * 2;
                float4 f0 = *(const float4*)(xr + (size_t)cc0 * HW + pxq * 4);
                float4 f1 = *(const float4*)(xr + (size_t)(cc0 + 1) * HW + pxq * 4);
                unsigned char* pl = EX + im * 24576 + (cc0 >> 6) * 12288;
                const int bo = (cc0 & 63) * 2;
                float a0[4] = {f0.x, f0.y, f0.z, f0.w};
                float a1[4] = {f1.x, f1.y, f1.z, f1.w};
#pragma unroll
                for (int r = 0; r < 4; ++r) {
                    unsigned int pk = (unsigned int)f2bf(a0[r]) |
                                      ((unsigned int)f2bf(a1[r]) << 16);
                    *(unsigned int*)(&pl[bswz(pxq * 4 + r, bo)]) = pk;
                }
            }
        }
    }

    // per-lane ws-offsets for B-loads; OOB px -> zero page
    unsigned offb[12];
#pragma unroll
    for (int cc = 0; cc < 4; ++cc)
#pragma unroll
        for (int g = 0; g < 3; ++g) {
            const int pxj = (wv * 3 + g) * 8 + li - 4;
            long off;
            if ((unsigned)pxj < 96u)
                off = (long)Y2_OFF +
                      ((long)(cc * 4 + hi) * NPIX + (long)b * HW +
                       (long)(h - 4) * 96 + pxj) * 16;
            else
                off = (long)ZP_OFF;
            offb[cc * 3 + g] = (unsigned)off;
        }

    // per-lane z2 offsets (col part); row walks by +384B per round
    int offz[3];
#pragma unroll
    for (int g = 0; g < 3; ++g) {
        const int zc = (wv * 3 + g) * 8 + li - 4;
        offz[g] = ((unsigned)zc < 96u)
            ? (int)Z2_OFF + (b * HW + (h - 4) * 96 + zc) * 4
            : (int)ZP_OFF;
    }

    const int imw = hi >> 1;     // image plane of this lane's D rows

    __syncthreads();

    // A-frags from swizzled Xs: row = li&7, image plane = li>>3
    bf16x8 afr[3][4];
    {
        const int imA = li >> 3;
        const int pA = li & 7;
#pragma unroll
        for (int g = 0; g < 3; ++g) {
            const int px = (wv * 3 + g) * 8 + pA;
#pragma unroll
            for (int cc = 0; cc < 4; ++cc) {
                const int k0 = cc * 32 + hi * 8;
                afr[g][cc] = *(const bf16x8*)(
                    &EX[imA * 24576 + (k0 >> 6) * 12288 + bswz(px, (k0 & 63) * 2)]);
            }
        }
    }
    __syncthreads();   // Xs consumed; EX is now Es

    // software pipeline over 10 rounds (6 early / 6 late prefetch, zv 1 ahead)
    uint4 pvA[2][6], pvB[2][6];
#pragma unroll
    for (int q = 0; q < 6; ++q)
        pvA[0][q] = *(const uint4*)(wsb + offb[q]);
#pragma unroll
    for (int q = 0; q < 6; ++q)
        pvB[0][q] = *(const uint4*)(wsb + offb[6 + q]);

    float zvc[3];
    {
        const int zok = ((unsigned)(h - 4) < 96u);
#pragma unroll
        for (int g = 0; g < 3; ++g)
            zvc[g] = *(const float*)(wsb + (zok ? offz[g] : (int)ZP_OFF));
    }

    const size_t obase = (size_t)b * 81 * HW + (size_t)h * 96;

#pragma unroll
    for (int di = 0; di < 10; ++di) {
        const int cur = di & 1, nxt = cur ^ 1;
        if (di < 9) {
#pragma unroll
            for (int q = 0; q < 6; ++q)
                pvA[nxt][q] = *(const uint4*)(wsb + offb[q] + (di + 1) * 1536);
        }

        const int hs = h - 4 + di;
        const int zrowok = ((unsigned)hs < 96u);

        f32x4 ac[3];
#pragma unroll
        for (int g = 0; g < 3; ++g) ac[g] = (f32x4){0.f, 0.f, 0.f, 0.f};

        if (zrowok) {     // block-uniform: skip MFMA for pad rows
#pragma unroll
            for (int cc = 0; cc < 4; ++cc)
#pragma unroll
                for (int g = 0; g < 3; ++g) {
                    union { uint4 u; bf16x8 f; } cv;
                    cv.u = (cc < 2) ? pvA[cur][cc * 3 + g]
                                    : pvB[cur][(cc - 2) * 3 + g];
                    ac[g] = __builtin_amdgcn_mfma_f32_16x16x32_bf16(
                        afr[g][cc], cv.f, ac[g], 0, 0, 0);
                }
        }

        if (di < 9) {
#pragma unroll
            for (int q = 0; q < 6; ++q)
                pvB[nxt][q] = *(const uint4*)(wsb + offb[6 + q] + (di + 1) * 1536);
        }

        float zvu[3];
#pragma unroll
        for (int g = 0; g < 3; ++g) zvu[g] = zvc[g];
        if (di < 9) {     // prefetch zv for next round
            const int zokn = ((unsigned)(hs + 1) < 96u);
#pragma unroll
            for (int g = 0; g < 3; ++g)
                zvc[g] = *(const float*)(wsb + (zokn ? offz[g] + (di + 1) * 384
                                                     : (int)ZP_OFF));
        }

        __syncthreads();   // Es[cur] store (round di-1) fully read; safe to write

        // band extract -> Es[cur]: local row = imw*9 + dji
        {
            const int rnd = di - imw;
            if ((unsigned)rnd < 9u) {
#pragma unroll
                for (int g = 0; g < 3; ++g) {
                    const int uu = wv * 3 + g;
#pragma unroll
                    for (int reg = 0; reg < 4; ++reg) {
                        const int ip = (hi & 1) * 4 + reg;   // px-in-group 0..7
                        const int dji = li - ip;
                        if (dji >= 0 && dji <= 8)
                            Es[cur * ESN + (imw * 9 + dji) * ESW + uu * 8 + ip] =
                                (ac[g][reg] + zvu[g]) * SCALE;
                    }
                }
            }
        }

        // store rows completed at round di-1 (from Es[nxt]); full 384B lines
        if (di >= 1) {
            const int dd = di - 1;
            for (int idx = t; idx < 1728; idx += 256) {
                const int p = idx / 864;            // plane 0/1
                const int r2 = idx - p * 864;
                const int r = r2 / 96, w = r2 - r * 96;
                const int rnd = dd - p;
                if ((unsigned)rnd < 9u)
                    out[obase + (size_t)(rnd * 9 + r) * HW + p * 96 + w] =
                        Es[nxt * ESN + (p * 9 + r) * ESW + w];
            }
        }
    }

    __syncthreads();
    // final store: rows completed at round 9 (plane1 rnd=8) from Es[1]
    {
        for (int idx = t; idx < 864; idx += 256) {
            const int r = idx / 96, w = idx - r * 96;
            out[obase + (size_t)(8 * 9 + r) * HW + 96 + w] =
                Es[1 * ESN + (9 + r) * ESW + w];
        }
    }
}

// ---------------- host ------------------------------------------------------
extern "C" void kernel_launch(void* const* d_in, const int* in_sizes, int n_in,
                              void* d_out, int out_size, void* d_ws, size_t ws_size,
                              hipStream_t stream) {
    const float* input1 = (const float*)d_in[0];
    const float* input2 = (const float*)d_in[1];
    const float* proj_w = (const float*)d_in[2];
    const float* proj_b = (const float*)d_in[3];
    float* out = (float*)d_out;

    char* ws = (char*)d_ws;
    if (ws_size < WS_NEED) return;  // fail loudly (output stays poisoned)

    unsigned short* Abuf = (unsigned short*)(ws + AB_OFF);
    float* vbuf = (float*)(ws + V_OFF);
    float* sbuf = (float*)(ws + S_OFF);
    unsigned short* y2 = (unsigned short*)(ws + Y2_OFF);
    float* z2 = (float*)(ws + Z2_OFF);
    char* zp = ws + ZP_OFF;

    k1_prep<<<dim3(144), dim3(128), 0, stream>>>(proj_w, proj_b, Abuf, vbuf, sbuf, zp);
    k2_proj<<<dim3(2304), dim3(512), 0, stream>>>(input2, Abuf, vbuf, sbuf, y2, z2);
    k3_corr<<<dim3(48, 32), dim3(256), 0, stream>>>(input1, ws, out);
}

// Round 10
// 166.644 us; speedup vs baseline: 1.3372x; 1.3372x over previous
//
#include <hip/hip_runtime.h>
#include <stdint.h>

#define B_   32
#define CIN  128
#define HH   96
#define WW   96
#define HW   (HH*WW)        // 9216
#define NPIX (B_*HW)        // 294912
#define AROWS 144
#define APAD  136           // bf16 elems per Asm row (272 B)
#define SCALE 0.08838834764831845f  // 1/sqrt(128)
#define ESW   98            // Es row stride in bf16 (196 B, 68 mod 128 -> spread)

// ws layout (bytes)
#define AB_OFF 0u
#define V_OFF  36864u
#define S_OFF  37376u
#define Y2_OFF 40960u
#define Z2_OFF (Y2_OFF + 75497472u)
#define ZP_OFF (Z2_OFF + 1179648u)          // 16 KB zero page
#define WS_NEED (ZP_OFF + 16384u)

typedef __attribute__((ext_vector_type(8))) short bf16x8;
typedef __attribute__((ext_vector_type(4))) float f32x4;

__device__ inline unsigned short f2bf(float f) {
    unsigned int u = __float_as_uint(f);
    u += 0x7fffu + ((u >> 16) & 1u);   // round-to-nearest-even
    return (unsigned short)(u >> 16);
}

// in-row XOR swizzle for 128B-aligned rows of 64 bf16: bijective (bits 4-6)
__device__ inline int bswz(int row, int byteoff) {
    return row * 128 + (byteoff ^ (((row ^ (row >> 3)) & 7) << 4));
}

// ---------------- K1: Abuf = [W^T W ; v ; 0], vbuf, sbuf, zero-page --------
__global__ __launch_bounds__(128) void k1_prep(
    const float* __restrict__ Wm, const float* __restrict__ bias,
    unsigned short* __restrict__ Abuf, float* __restrict__ vbuf,
    float* __restrict__ sbuf, char* __restrict__ zp) {
    int r = blockIdx.x;      // 0..143
    int c = threadIdx.x;     // 0..127
    int gid = r * 128 + c;
    if (gid < 1024)
        *(uint4*)(zp + gid * 16) = make_uint4(0u, 0u, 0u, 0u);

    float acc = 0.f;
    if (r < 128) {
        for (int f = 0; f < 128; ++f)
            acc += Wm[f * 128 + r] * Wm[f * 128 + c];
    } else if (r == 128) {
        for (int f = 0; f < 128; ++f)
            acc += Wm[f * 128 + c] * bias[f];
        vbuf[c] = acc;
        if (c == 0) {
            float s = 0.f;
            for (int f = 0; f < 128; ++f) s += bias[f] * bias[f];
            sbuf[0] = s;
        }
    }
    Abuf[r * 128 + c] = f2bf(acc);
}

// ---- K2: y2[seg][b][hw][8ch] = (M a2 + v) bf16 planar; z2 = v.a2 + s ------
__global__ __launch_bounds__(512, 4) void k2_proj(
    const float* __restrict__ a2, const unsigned short* __restrict__ Abuf,
    const float* __restrict__ vbuf, const float* __restrict__ sbuf,
    unsigned short* __restrict__ y2, float* __restrict__ z2) {
    __shared__ __align__(16) unsigned short Asm[AROWS * APAD];   // 39168 B
    __shared__ __align__(128) unsigned char Bsm[2][128 * 128];   // 32768 B

    const int t = threadIdx.x;
    const int tile = blockIdx.x;          // 0..2303
    const int b = tile / 72;
    const int hw0 = (tile - b * 72) * 128;

    for (int i = t; i < 2304; i += 512) {
        int row = i >> 4, seg = i & 15;
        *(uint4*)(&Asm[row * APAD + seg * 8]) =
            *(const uint4*)(Abuf + row * 128 + seg * 8);
    }

    {
        const int pxq = t & 31;           // px quad 0..31
        const int ctp = t >> 5;           // ch-pair 0..15
        const float* a2b = a2 + (size_t)b * (CIN * HW) + hw0 + pxq * 4;
#pragma unroll
        for (int it = 0; it < 4; ++it) {
            const int cc0 = (ctp + it * 16) * 2;      // even channel
            float4 f0 = *(const float4*)(a2b + (size_t)cc0 * HW);
            float4 f1 = *(const float4*)(a2b + (size_t)(cc0 + 1) * HW);
            unsigned char* pl = Bsm[cc0 >> 6];
            const int bo = (cc0 & 63) * 2;
            float a0[4] = {f0.x, f0.y, f0.z, f0.w};
            float a1[4] = {f1.x, f1.y, f1.z, f1.w};
#pragma unroll
            for (int r = 0; r < 4; ++r) {
                unsigned int pk = (unsigned int)f2bf(a0[r]) |
                                  ((unsigned int)f2bf(a1[r]) << 16);
                *(unsigned int*)(&pl[bswz(pxq * 4 + r, bo)]) = pk;
            }
        }
    }
    __syncthreads();

    const int wv = t >> 6;
    const int l = t & 63;
    const int li = l & 15;
    const int hi = l >> 4;
    const int rbase = hi * 4;
    const int pxl = wv * 16 + li;

    bf16x8 bfr[4];
#pragma unroll
    for (int kk = 0; kk < 4; ++kk) {
        const int k0 = kk * 32 + hi * 8;
        bfr[kk] = *(const bf16x8*)(&Bsm[k0 >> 6][bswz(pxl, (k0 & 63) * 2)]);
    }

    f32x4 acc[9];
#pragma unroll
    for (int m = 0; m < 9; ++m) acc[m] = (f32x4){0.f, 0.f, 0.f, 0.f};

#pragma unroll
    for (int kk = 0; kk < 4; ++kk) {
        const int k0 = kk * 32 + hi * 8;
#pragma unroll
        for (int m = 0; m < 9; ++m) {
            bf16x8 af = *(const bf16x8*)(&Asm[(m * 16 + li) * APAD + k0]);
            acc[m] = __builtin_amdgcn_mfma_f32_16x16x32_bf16(af, bfr[kk], acc[m], 0, 0, 0);
        }
    }

    const int px = hw0 + pxl;
    const size_t pxoff = (size_t)b * HW + px;
#pragma unroll
    for (int m = 0; m < 8; ++m) {
        int c0 = m * 16 + rbase;
        ushort4 pk;
        pk.x = f2bf(acc[m].x + vbuf[c0 + 0]);
        pk.y = f2bf(acc[m].y + vbuf[c0 + 1]);
        pk.z = f2bf(acc[m].z + vbuf[c0 + 2]);
        pk.w = f2bf(acc[m].w + vbuf[c0 + 3]);
        *(ushort4*)(y2 + ((size_t)(c0 >> 3) * NPIX + pxoff) * 8 + (c0 & 7)) = pk;
    }
    if (rbase == 0) {
        z2[pxoff] = acc[8].x + sbuf[0];
    }
}

// -------- K3: MFMA correlation, 2 image rows packed per 16-row A-tile ------
// A rows 0-7 = row h px window, rows 8-15 = row h+1 same window.
// Round di (0..9): B row hs = h-4+di; plane0 shift-row di, plane1 shift-row di-1.
// Es staged in bf16 (31.8 KB, aliases Xs) -> LDS 49.2 KB -> 3 blocks/CU.
__global__ __launch_bounds__(256, 3) void k3_corr(
    const float* __restrict__ x1, const char* __restrict__ wsb,
    float* __restrict__ out) {
    // Xs: [2 im][2 chplane][96 rows][64 bf16] = 49152 B ; Es alias: 31752 B
    __shared__ __align__(128) unsigned char EX[49152];
    unsigned short* Es16 = (unsigned short*)EX;

    const int t = threadIdx.x;
    const int bx = blockIdx.x;                 // 0..47
    const int b = blockIdx.y;
    const int h = ((bx & 7) * 6 + (bx >> 3)) * 2;   // XCD-chunked, bijective

    const int wv = t >> 6;       // wave 0..3
    const int l = t & 63;
    const int li = l & 15;
    const int hi = l >> 4;

    // stage Xs: 2 image rows, [128 ch][96 px] f32 -> swizzled bf16 planes
    {
        const float* x1b = x1 + (size_t)b * (CIN * HW) + (size_t)h * 96;
#pragma unroll
        for (int im = 0; im < 2; ++im) {
            const float* xr = x1b + im * 96;
#pragma unroll
            for (int it = 0; it < 6; ++it) {
                int idx = t + it * 256;           // 0..1535
                int ccp = idx / 24;               // 0..63
                int pxq = idx - ccp * 24;         // 0..23
                int cc0 = ccp * 2;
                float4 f0 = *(const float4*)(xr + (size_t)cc0 * HW + pxq * 4);
                float4 f1 = *(const float4*)(xr + (size_t)(cc0 + 1) * HW + pxq * 4);
                unsigned char* pl = EX + im * 24576 + (cc0 >> 6) * 12288;
                const int bo = (cc0 & 63) * 2;
                float a0[4] = {f0.x, f0.y, f0.z, f0.w};
                float a1[4] = {f1.x, f1.y, f1.z, f1.w};
#pragma unroll
                for (int r = 0; r < 4; ++r) {
                    unsigned int pk = (unsigned int)f2bf(a0[r]) |
                                      ((unsigned int)f2bf(a1[r]) << 16);
                    *(unsigned int*)(&pl[bswz(pxq * 4 + r, bo)]) = pk;
                }
            }
        }
    }

    // per-lane ws-offsets for B-loads; OOB px -> zero page
    unsigned offb[12];
#pragma unroll
    for (int cc = 0; cc < 4; ++cc)
#pragma unroll
        for (int g = 0; g < 3; ++g) {
            const int pxj = (wv * 3 + g) * 8 + li - 4;
            long off;
            if ((unsigned)pxj < 96u)
                off = (long)Y2_OFF +
                      ((long)(cc * 4 + hi) * NPIX + (long)b * HW +
                       (long)(h - 4) * 96 + pxj) * 16;
            else
                off = (long)ZP_OFF;
            offb[cc * 3 + g] = (unsigned)off;
        }

    // per-lane z2 offsets (col part); row walks by +384B per round
    int offz[3];
#pragma unroll
    for (int g = 0; g < 3; ++g) {
        const int zc = (wv * 3 + g) * 8 + li - 4;
        offz[g] = ((unsigned)zc < 96u)
            ? (int)Z2_OFF + (b * HW + (h - 4) * 96 + zc) * 4
            : (int)ZP_OFF;
    }

    const int imw = hi >> 1;     // image plane of this lane's D rows

    __syncthreads();

    // A-frags from swizzled Xs: row = li&7, image plane = li>>3
    bf16x8 afr[3][4];
    {
        const int imA = li >> 3;
        const int pA = li & 7;
#pragma unroll
        for (int g = 0; g < 3; ++g) {
            const int px = (wv * 3 + g) * 8 + pA;
#pragma unroll
            for (int cc = 0; cc < 4; ++cc) {
                const int k0 = cc * 32 + hi * 8;
                afr[g][cc] = *(const bf16x8*)(
                    &EX[imA * 24576 + (k0 >> 6) * 12288 + bswz(px, (k0 & 63) * 2)]);
            }
        }
    }
    __syncthreads();   // Xs consumed; EX is now Es16

    // software pipeline over 10 rounds (6 early / 6 late prefetch)
    uint4 pvA[2][6], pvB[2][6];
#pragma unroll
    for (int q = 0; q < 6; ++q)
        pvA[0][q] = *(const uint4*)(wsb + offb[q]);
#pragma unroll
    for (int q = 0; q < 6; ++q)
        pvB[0][q] = *(const uint4*)(wsb + offb[6 + q]);

#pragma unroll
    for (int di = 0; di < 10; ++di) {
        const int cur = di & 1, nxt = cur ^ 1;
        if (di < 9) {
#pragma unroll
            for (int q = 0; q < 6; ++q)
                pvA[nxt][q] = *(const uint4*)(wsb + offb[q] + (di + 1) * 1536);
        }

        const int hs = h - 4 + di;
        const int zrowok = ((unsigned)hs < 96u);
        float zv[3];
#pragma unroll
        for (int g = 0; g < 3; ++g)
            zv[g] = *(const float*)(wsb + (zrowok ? offz[g] + di * 384
                                                  : (int)ZP_OFF));

        f32x4 ac[3];
#pragma unroll
        for (int g = 0; g < 3; ++g) ac[g] = (f32x4){0.f, 0.f, 0.f, 0.f};

        if (zrowok) {     // block-uniform: skip MFMA for pad rows
#pragma unroll
            for (int cc = 0; cc < 4; ++cc)
#pragma unroll
                for (int g = 0; g < 3; ++g) {
                    union { uint4 u; bf16x8 f; } cv;
                    cv.u = (cc < 2) ? pvA[cur][cc * 3 + g]
                                    : pvB[cur][(cc - 2) * 3 + g];
                    ac[g] = __builtin_amdgcn_mfma_f32_16x16x32_bf16(
                        afr[g][cc], cv.f, ac[g], 0, 0, 0);
                }
        }

        // band extract -> Es16 (bf16), each cell written exactly once
        {
            const int rnd = di - imw;
            if ((unsigned)rnd < 9u) {
#pragma unroll
                for (int g = 0; g < 3; ++g) {
                    const int uu = wv * 3 + g;
#pragma unroll
                    for (int reg = 0; reg < 4; ++reg) {
                        const int ip = (hi & 1) * 4 + reg;   // px-in-group 0..7
                        const int dji = li - ip;
                        if (dji >= 0 && dji <= 8)
                            Es16[(imw * 81 + rnd * 9 + dji) * ESW + uu * 8 + ip] =
                                f2bf((ac[g][reg] + zv[g]) * SCALE);
                    }
                }
            }
        }

        if (di < 9) {
#pragma unroll
            for (int q = 0; q < 6; ++q)
                pvB[nxt][q] = *(const uint4*)(wsb + offb[6 + q] + (di + 1) * 1536);
        }
    }

    __syncthreads();
    // bulk coalesced store: 2 rows x 81 planes x 96 w ; bf16 pairs -> f32x2
    const size_t obase = (size_t)b * 81 * HW + (size_t)h * 96;
    for (int idx = t; idx < 7776; idx += 256) {
        const int p = idx / 3888;               // image plane 0/1
        const int r2 = idx - p * 3888;
        const int s = r2 / 48, w2 = r2 - s * 48;
        unsigned u = *(const unsigned*)(&Es16[(p * 81 + s) * ESW + w2 * 2]);
        float2 fv;
        fv.x = __uint_as_float(u << 16);
        fv.y = __uint_as_float(u & 0xffff0000u);
        *(float2*)(&out[obase + (size_t)s * HW + p * 96 + w2 * 2]) = fv;
    }
}

// ---------------- host ------------------------------------------------------
extern "C" void kernel_launch(void* const* d_in, const int* in_sizes, int n_in,
                              void* d_out, int out_size, void* d_ws, size_t ws_size,
                              hipStream_t stream) {
    const float* input1 = (const float*)d_in[0];
    const float* input2 = (const float*)d_in[1];
    const float* proj_w = (const float*)d_in[2];
    const float* proj_b = (const float*)d_in[3];
    float* out = (float*)d_out;

    char* ws = (char*)d_ws;
    if (ws_size < WS_NEED) return;  // fail loudly (output stays poisoned)

    unsigned short* Abuf = (unsigned short*)(ws + AB_OFF);
    float* vbuf = (float*)(ws + V_OFF);
    float* sbuf = (float*)(ws + S_OFF);
    unsigned short* y2 = (unsigned short*)(ws + Y2_OFF);
    float* z2 = (float*)(ws + Z2_OFF);
    char* zp = ws + ZP_OFF;

    k1_prep<<<dim3(144), dim3(128), 0, stream>>>(proj_w, proj_b, Abuf, vbuf, sbuf, zp);
    k2_proj<<<dim3(2304), dim3(512), 0, stream>>>(input2, Abuf, vbuf, sbuf, y2, z2);
    k3_corr<<<dim3(48, 32), dim3(256), 0, stream>>>(input1, ws, out);
}

// Round 11
// 152.043 us; speedup vs baseline: 1.4656x; 1.0960x over previous
//
#include <hip/hip_runtime.h>
#include <stdint.h>

#define B_   32
#define CIN  128
#define HH   96
#define WW   96
#define HW   (HH*WW)        // 9216
#define NPIX (B_*HW)        // 294912
#define AROWS 144
#define APAD  136           // bf16 elems per Asm row (272 B)
#define SCALE 0.08838834764831845f  // 1/sqrt(128)
#define ESW   98            // Es row stride in bf16 (196 B)

// ws layout (bytes)
#define AB_OFF 0u
#define V_OFF  36864u
#define S_OFF  37376u
#define Y2_OFF 40960u
#define Z2_OFF (Y2_OFF + 75497472u)
#define ZP_OFF (Z2_OFF + 1179648u)          // 16 KB zero page
#define WS_NEED (ZP_OFF + 16384u)

typedef __attribute__((ext_vector_type(8))) short bf16x8;
typedef __attribute__((ext_vector_type(4))) float f32x4;

__device__ inline unsigned short f2bf(float f) {
    unsigned int u = __float_as_uint(f);
    u += 0x7fffu + ((u >> 16) & 1u);   // round-to-nearest-even
    return (unsigned short)(u >> 16);
}

// in-row XOR swizzle for 128B-aligned rows of 64 bf16: bijective (bits 4-6)
__device__ inline int bswz(int row, int byteoff) {
    return row * 128 + (byteoff ^ (((row ^ (row >> 3)) & 7) << 4));
}

// ---------------- K1: Abuf = [W^T W ; v ; 0], vbuf, sbuf, zero-page --------
__global__ __launch_bounds__(128) void k1_prep(
    const float* __restrict__ Wm, const float* __restrict__ bias,
    unsigned short* __restrict__ Abuf, float* __restrict__ vbuf,
    float* __restrict__ sbuf, char* __restrict__ zp) {
    int r = blockIdx.x;      // 0..143
    int c = threadIdx.x;     // 0..127
    int gid = r * 128 + c;
    if (gid < 1024)
        *(uint4*)(zp + gid * 16) = make_uint4(0u, 0u, 0u, 0u);

    float acc = 0.f;
    if (r < 128) {
        for (int f = 0; f < 128; ++f)
            acc += Wm[f * 128 + r] * Wm[f * 128 + c];
    } else if (r == 128) {
        for (int f = 0; f < 128; ++f)
            acc += Wm[f * 128 + c] * bias[f];
        vbuf[c] = acc;
        if (c == 0) {
            float s = 0.f;
            for (int f = 0; f < 128; ++f) s += bias[f] * bias[f];
            sbuf[0] = s;
        }
    }
    Abuf[r * 128 + c] = f2bf(acc);
}

// ---- K2: y2[seg][b][hw][8ch] = (M a2 + v) bf16 planar; z2 = v.a2 + s ------
__global__ __launch_bounds__(512, 4) void k2_proj(
    const float* __restrict__ a2, const unsigned short* __restrict__ Abuf,
    const float* __restrict__ vbuf, const float* __restrict__ sbuf,
    unsigned short* __restrict__ y2, float* __restrict__ z2) {
    __shared__ __align__(16) unsigned short Asm[AROWS * APAD];   // 39168 B
    __shared__ __align__(128) unsigned char Bsm[2][128 * 128];   // 32768 B

    const int t = threadIdx.x;
    const int tile = blockIdx.x;          // 0..2303
    const int b = tile / 72;
    const int hw0 = (tile - b * 72) * 128;

    for (int i = t; i < 2304; i += 512) {
        int row = i >> 4, seg = i & 15;
        *(uint4*)(&Asm[row * APAD + seg * 8]) =
            *(const uint4*)(Abuf + row * 128 + seg * 8);
    }

    {
        const int pxq = t & 31;           // px quad 0..31
        const int ctp = t >> 5;           // ch-pair 0..15
        const float* a2b = a2 + (size_t)b * (CIN * HW) + hw0 + pxq * 4;
#pragma unroll
        for (int it = 0; it < 4; ++it) {
            const int cc0 = (ctp + it * 16) * 2;      // even channel
            float4 f0 = *(const float4*)(a2b + (size_t)cc0 * HW);
            float4 f1 = *(const float4*)(a2b + (size_t)(cc0 + 1) * HW);
            unsigned char* pl = Bsm[cc0 >> 6];
            const int bo = (cc0 & 63) * 2;
            float a0[4] = {f0.x, f0.y, f0.z, f0.w};
            float a1[4] = {f1.x, f1.y, f1.z, f1.w};
#pragma unroll
            for (int r = 0; r < 4; ++r) {
                unsigned int pk = (unsigned int)f2bf(a0[r]) |
                                  ((unsigned int)f2bf(a1[r]) << 16);
                *(unsigned int*)(&pl[bswz(pxq * 4 + r, bo)]) = pk;
            }
        }
    }
    __syncthreads();

    const int wv = t >> 6;
    const int l = t & 63;
    const int li = l & 15;
    const int hi = l >> 4;
    const int rbase = hi * 4;
    const int pxl = wv * 16 + li;

    bf16x8 bfr[4];
#pragma unroll
    for (int kk = 0; kk < 4; ++kk) {
        const int k0 = kk * 32 + hi * 8;
        bfr[kk] = *(const bf16x8*)(&Bsm[k0 >> 6][bswz(pxl, (k0 & 63) * 2)]);
    }

    f32x4 acc[9];
#pragma unroll
    for (int m = 0; m < 9; ++m) acc[m] = (f32x4){0.f, 0.f, 0.f, 0.f};

#pragma unroll
    for (int kk = 0; kk < 4; ++kk) {
        const int k0 = kk * 32 + hi * 8;
#pragma unroll
        for (int m = 0; m < 9; ++m) {
            bf16x8 af = *(const bf16x8*)(&Asm[(m * 16 + li) * APAD + k0]);
            acc[m] = __builtin_amdgcn_mfma_f32_16x16x32_bf16(af, bfr[kk], acc[m], 0, 0, 0);
        }
    }

    const int px = hw0 + pxl;
    const size_t pxoff = (size_t)b * HW + px;
#pragma unroll
    for (int m = 0; m < 8; ++m) {
        int c0 = m * 16 + rbase;
        ushort4 pk;
        pk.x = f2bf(acc[m].x + vbuf[c0 + 0]);
        pk.y = f2bf(acc[m].y + vbuf[c0 + 1]);
        pk.z = f2bf(acc[m].z + vbuf[c0 + 2]);
        pk.w = f2bf(acc[m].w + vbuf[c0 + 3]);
        *(ushort4*)(y2 + ((size_t)(c0 >> 3) * NPIX + pxoff) * 8 + (c0 & 7)) = pk;
    }
    if (rbase == 0) {
        z2[pxoff] = acc[8].x + sbuf[0];
    }
}

// -------- K3: MFMA correlation, 2 image rows packed per 16-row A-tile ------
// 2-deep software pipeline: round di consumes pv[di&1], then reissues that
// buffer for round di+2 (~2 rounds of latency coverage). 2 blocks/CU keeps
// the per-XCD y2 working set L2-resident (R10 lesson: 3 blocks thrashed L2).
__global__ __launch_bounds__(256, 2) void k3_corr(
    const float* __restrict__ x1, const char* __restrict__ wsb,
    float* __restrict__ out) {
    // Xs: [2 im][2 chplane][96 rows][64 bf16] = 49152 B ; Es16 alias: 31752 B
    __shared__ __align__(128) unsigned char EX[49152];
    unsigned short* Es16 = (unsigned short*)EX;

    const int t = threadIdx.x;
    const int bx = blockIdx.x;                 // 0..47
    const int b = blockIdx.y;
    const int h = ((bx & 7) * 6 + (bx >> 3)) * 2;   // XCD-chunked, bijective

    const int wv = t >> 6;       // wave 0..3
    const int l = t & 63;
    const int li = l & 15;
    const int hi = l >> 4;

    // stage Xs: 2 image rows, [128 ch][96 px] f32 -> swizzled bf16 planes
    {
        const float* x1b = x1 + (size_t)b * (CIN * HW) + (size_t)h * 96;
#pragma unroll
        for (int im = 0; im < 2; ++im) {
            const float* xr = x1b + im * 96;
#pragma unroll
            for (int it = 0; it < 6; ++it) {
                int idx = t + it * 256;           // 0..1535
                int ccp = idx / 24;               // 0..63
                int pxq = idx - ccp * 24;         // 0..23
                int cc0 = ccp * 2;
                float4 f0 = *(const float4*)(xr + (size_t)cc0 * HW + pxq * 4);
                float4 f1 = *(const float4*)(xr + (size_t)(cc0 + 1) * HW + pxq * 4);
                unsigned char* pl = EX + im * 24576 + (cc0 >> 6) * 12288;
                const int bo = (cc0 & 63) * 2;
                float a0[4] = {f0.x, f0.y, f0.z, f0.w};
                float a1[4] = {f1.x, f1.y, f1.z, f1.w};
#pragma unroll
                for (int r = 0; r < 4; ++r) {
                    unsigned int pk = (unsigned int)f2bf(a0[r]) |
                                      ((unsigned int)f2bf(a1[r]) << 16);
                    *(unsigned int*)(&pl[bswz(pxq * 4 + r, bo)]) = pk;
                }
            }
        }
    }

    // per-lane ws-offsets for B-loads; OOB px -> zero page
    unsigned offb[12];
#pragma unroll
    for (int cc = 0; cc < 4; ++cc)
#pragma unroll
        for (int g = 0; g < 3; ++g) {
            const int pxj = (wv * 3 + g) * 8 + li - 4;
            long off;
            if ((unsigned)pxj < 96u)
                off = (long)Y2_OFF +
                      ((long)(cc * 4 + hi) * NPIX + (long)b * HW +
                       (long)(h - 4) * 96 + pxj) * 16;
            else
                off = (long)ZP_OFF;
            offb[cc * 3 + g] = (unsigned)off;
        }

    // per-lane z2 offsets (col part); row walks by +384B per round
    int offz[3];
#pragma unroll
    for (int g = 0; g < 3; ++g) {
        const int zc = (wv * 3 + g) * 8 + li - 4;
        offz[g] = ((unsigned)zc < 96u)
            ? (int)Z2_OFF + (b * HW + (h - 4) * 96 + zc) * 4
            : (int)ZP_OFF;
    }

    const int imw = hi >> 1;     // image plane of this lane's D rows

    __syncthreads();

    // A-frags from swizzled Xs: row = li&7, image plane = li>>3
    bf16x8 afr[3][4];
    {
        const int imA = li >> 3;
        const int pA = li & 7;
#pragma unroll
        for (int g = 0; g < 3; ++g) {
            const int px = (wv * 3 + g) * 8 + pA;
#pragma unroll
            for (int cc = 0; cc < 4; ++cc) {
                const int k0 = cc * 32 + hi * 8;
                afr[g][cc] = *(const bf16x8*)(
                    &EX[imA * 24576 + (k0 >> 6) * 12288 + bswz(px, (k0 & 63) * 2)]);
            }
        }
    }
    __syncthreads();   // Xs consumed; EX is now Es16

    // ---- 2-deep pipeline prologue: issue rounds 0 and 1, zv for 0 and 1 ----
    uint4 pv[2][12];
#pragma unroll
    for (int q = 0; q < 12; ++q)
        pv[0][q] = *(const uint4*)(wsb + offb[q]);
#pragma unroll
    for (int q = 0; q < 12; ++q)
        pv[1][q] = *(const uint4*)(wsb + offb[q] + 1536);

    float zvc[2][3];
#pragma unroll
    for (int r0 = 0; r0 < 2; ++r0) {
        const int zok = ((unsigned)(h - 4 + r0) < 96u);
#pragma unroll
        for (int g = 0; g < 3; ++g)
            zvc[r0][g] = *(const float*)(wsb + (zok ? offz[g] + r0 * 384
                                                    : (int)ZP_OFF));
    }

#pragma unroll
    for (int di = 0; di < 10; ++di) {
        const int cur = di & 1;
        const int hs = h - 4 + di;
        const int zrowok = ((unsigned)hs < 96u);

        f32x4 ac[3];
#pragma unroll
        for (int g = 0; g < 3; ++g) ac[g] = (f32x4){0.f, 0.f, 0.f, 0.f};

        if (zrowok) {     // block-uniform: skip MFMA for pad rows
#pragma unroll
            for (int cc = 0; cc < 4; ++cc)
#pragma unroll
                for (int g = 0; g < 3; ++g) {
                    union { uint4 u; bf16x8 f; } cv;
                    cv.u = pv[cur][cc * 3 + g];
                    ac[g] = __builtin_amdgcn_mfma_f32_16x16x32_bf16(
                        afr[g][cc], cv.f, ac[g], 0, 0, 0);
                }
        }

        // reissue the just-consumed buffer for round di+2 (2 rounds ahead)
        if (di < 8) {
#pragma unroll
            for (int q = 0; q < 12; ++q)
                pv[cur][q] = *(const uint4*)(wsb + offb[q] + (di + 2) * 1536);
        }

        // band extract -> Es16 (bf16), each cell written exactly once
        {
            const int rnd = di - imw;
            if ((unsigned)rnd < 9u) {
#pragma unroll
                for (int g = 0; g < 3; ++g) {
                    const int uu = wv * 3 + g;
#pragma unroll
                    for (int reg = 0; reg < 4; ++reg) {
                        const int ip = (hi & 1) * 4 + reg;   // px-in-group 0..7
                        const int dji = li - ip;
                        if (dji >= 0 && dji <= 8)
                            Es16[(imw * 81 + rnd * 9 + dji) * ESW + uu * 8 + ip] =
                                f2bf((ac[g][reg] + zvc[cur][g]) * SCALE);
                    }
                }
            }
        }

        // zv prefetch for round di+2 (after extract consumed zvc[cur])
        if (di < 8) {
            const int zokn = ((unsigned)(hs + 2) < 96u);
#pragma unroll
            for (int g = 0; g < 3; ++g)
                zvc[cur][g] = *(const float*)(wsb + (zokn ? offz[g] + (di + 2) * 384
                                                          : (int)ZP_OFF));
        }
    }

    __syncthreads();
    // bulk coalesced store: 2 rows x 81 planes x 96 w ; bf16 pairs -> f32x2
    const size_t obase = (size_t)b * 81 * HW + (size_t)h * 96;
    for (int idx = t; idx < 7776; idx += 256) {
        const int p = idx / 3888;               // image plane 0/1
        const int r2 = idx - p * 3888;
        const int s = r2 / 48, w2 = r2 - s * 48;
        unsigned u = *(const unsigned*)(&Es16[(p * 81 + s) * ESW + w2 * 2]);
        float2 fv;
        fv.x = __uint_as_float(u << 16);
        fv.y = __uint_as_float(u & 0xffff0000u);
        *(float2*)(&out[obase + (size_t)s * HW + p * 96 + w2 * 2]) = fv;
    }
}

// ---------------- host ------------------------------------------------------
extern "C" void kernel_launch(void* const* d_in, const int* in_sizes, int n_in,
                              void* d_out, int out_size, void* d_ws, size_t ws_size,
                              hipStream_t stream) {
    const float* input1 = (const float*)d_in[0];
    const float* input2 = (const float*)d_in[1];
    const float* proj_w = (const float*)d_in[2];
    const float* proj_b = (const float*)d_in[3];
    float* out = (float*)d_out;

    char* ws = (char*)d_ws;
    if (ws_size < WS_NEED) return;  // fail loudly (output stays poisoned)

    unsigned short* Abuf = (unsigned short*)(ws + AB_OFF);
    float* vbuf = (float*)(ws + V_OFF);
    float* sbuf = (float*)(ws + S_OFF);
    unsigned short* y2 = (unsigned short*)(ws + Y2_OFF);
    float* z2 = (float*)(ws + Z2_OFF);
    char* zp = ws + ZP_OFF;

    k1_prep<<<dim3(144), dim3(128), 0, stream>>>(proj_w, proj_b, Abuf, vbuf, sbuf, zp);
    k2_proj<<<dim3(2304), dim3(512), 0, stream>>>(input2, Abuf, vbuf, sbuf, y2, z2);
    k3_corr<<<dim3(48, 32), dim3(256), 0, stream>>>(input1, ws, out);
}